// Round 3
// baseline (390.254 us; speedup 1.0000x reference)
//
#include <hip/hip_runtime.h>

#define L_SEQ 2048
#define BATCH 32
#define HID   1024
#define FLOAT_MIN -1e20f

// ---------------------------------------------------------------------------
// Kernel 1: v[b,h] = sum_g hidden[b,g] * W[g,h];  c[b] = sum_g hidden[b,g]*bias[g]
// Grid: 256 blocks -> b = bid/8, n-tile(128 cols) = bid%8. 256 threads.
// W column-tile is re-read per b but stays L2/L3 resident (W = 4 MB total).
// ---------------------------------------------------------------------------
__global__ __launch_bounds__(256) void proj_kernel(
    const float* __restrict__ hidden,   // [B,H]
    const float* __restrict__ W,        // [H,H]  (g-major, h contiguous)
    const float* __restrict__ bias,     // [H]
    float* __restrict__ v,              // [B,H]
    float* __restrict__ c)              // [B]
{
    __shared__ float  sh_hidden[HID];
    __shared__ float4 sh_part[8][32];
    __shared__ float  sh_red[4];

    const int b  = blockIdx.x >> 3;
    const int nt = blockIdx.x & 7;
    const int t  = threadIdx.x;

    // stage hidden[b,:] (4 KB) into LDS
    ((float4*)sh_hidden)[t] = ((const float4*)(hidden + (size_t)b * HID))[t];
    __syncthreads();

    const int j4   = t & 31;    // float4 column within the 128-col tile
    const int half = t >> 5;    // 0..7 : k-partition of 128 rows each
    const int n0   = nt * 128;

    float4 acc = make_float4(0.f, 0.f, 0.f, 0.f);
    const int kbase = half * 128;
    #pragma unroll 4
    for (int k = kbase; k < kbase + 128; ++k) {
        const float  hg = sh_hidden[k];                          // LDS broadcast
        const float4 w  = ((const float4*)(W + (size_t)k * HID + n0))[j4];
        acc.x += hg * w.x; acc.y += hg * w.y;
        acc.z += hg * w.z; acc.w += hg * w.w;
    }
    sh_part[half][j4] = acc;
    __syncthreads();

    if (t < 32) {
        float4 s = sh_part[0][t];
        #pragma unroll
        for (int h = 1; h < 8; ++h) {
            const float4 p = sh_part[h][t];
            s.x += p.x; s.y += p.y; s.z += p.z; s.w += p.w;
        }
        ((float4*)(v + (size_t)b * HID + n0))[t] = s;
    }

    if (nt == 0) {  // block-uniform branch: compute c[b] once per b
        float p = 0.f;
        #pragma unroll
        for (int g = t; g < HID; g += 256) p += sh_hidden[g] * bias[g];
        #pragma unroll
        for (int off = 32; off > 0; off >>= 1) p += __shfl_down(p, off, 64);
        if ((t & 63) == 0) sh_red[t >> 6] = p;
        __syncthreads();
        if (t == 0) c[b] = sh_red[0] + sh_red[1] + sh_red[2] + sh_red[3];
    }
}

// ---------------------------------------------------------------------------
// Kernel 2: energies[b,l] = v[b] . enc[l,b,:] + c[b]
// One wave <-> fixed b: v[b]'s per-lane fragment lives in 16 VGPRs for the
// whole kernel (eliminates ~256 MB of redundant v reads from L2). Each wave
// loops over 16 l-rows; each row is a 4 KB contiguous burst (4x dwordx4/wave).
// Grid: B * 32 = 1024 blocks x 256 thr -> 16 waves/CU, ~8 loads in flight/wave.
// ---------------------------------------------------------------------------
__global__ __launch_bounds__(256) void energy_kernel(
    const float* __restrict__ enc,      // [L,B,H]
    const float* __restrict__ v,        // [B,H]
    const float* __restrict__ c,        // [B]
    float* __restrict__ energies)       // [B,L]
{
    const int t     = threadIdx.x;
    const int wave  = t >> 6;
    const int lane  = t & 63;
    const int b     = blockIdx.x >> 5;      // 0..31
    const int chunk = blockIdx.x & 31;      // 0..31 -> 64-row l window

    // register-cache v[b]: lane holds float4 j*64+lane, j=0..3 (16 VGPRs)
    const float4* vp = (const float4*)(v + (size_t)b * HID);
    const float4 v0 = vp[0 * 64 + lane];
    const float4 v1 = vp[1 * 64 + lane];
    const float4 v2 = vp[2 * 64 + lane];
    const float4 v3 = vp[3 * 64 + lane];
    const float  cb = c[b];

    const int lbase = chunk * 64 + wave;    // wave covers lbase + 4*i, i=0..15
    float* eout = energies + (size_t)b * L_SEQ;

    #pragma unroll 2
    for (int i = 0; i < 16; ++i) {
        const int l = lbase + 4 * i;
        const float4* ep = (const float4*)(enc + ((size_t)l * BATCH + b) * HID);
        const float4 e0 = ep[0 * 64 + lane];
        const float4 e1 = ep[1 * 64 + lane];
        const float4 e2 = ep[2 * 64 + lane];
        const float4 e3 = ep[3 * 64 + lane];
        float a = e0.x * v0.x + e0.y * v0.y + e0.z * v0.z + e0.w * v0.w
                + e1.x * v1.x + e1.y * v1.y + e1.z * v1.z + e1.w * v1.w
                + e2.x * v2.x + e2.y * v2.y + e2.z * v2.z + e2.w * v2.w
                + e3.x * v3.x + e3.y * v3.y + e3.z * v3.z + e3.w * v3.w;
        #pragma unroll
        for (int off = 32; off > 0; off >>= 1) a += __shfl_down(a, off, 64);
        if (lane == 0) eout[l] = a + cb;
    }
}

// ---------------------------------------------------------------------------
// Kernel 3: masked softmax per batch row, renormalized over valid positions.
// Invalid l get energy FLOAT_MIN -> exp underflows to exact 0, so plain
// softmax over the masked energies equals the reference's masked/sums.
// Grid: B blocks, 256 threads, 8 elements/thread.
// ---------------------------------------------------------------------------
__global__ __launch_bounds__(256) void softmax_kernel(
    const float* __restrict__ energies, // [B,L]
    const int*   __restrict__ lengths,  // [B]
    float* __restrict__ out)            // [B,1,L]
{
    __shared__ float red[4];

    const int b   = blockIdx.x;
    const int t   = threadIdx.x;
    const int len = lengths[b];

    float e[8];
    float m = -INFINITY;
    #pragma unroll
    for (int i = 0; i < 8; ++i) {
        const int l = t + i * 256;
        e[i] = (l < len) ? energies[(size_t)b * L_SEQ + l] : FLOAT_MIN;
        m = fmaxf(m, e[i]);
    }
    #pragma unroll
    for (int off = 32; off > 0; off >>= 1) m = fmaxf(m, __shfl_down(m, off, 64));
    if ((t & 63) == 0) red[t >> 6] = m;
    __syncthreads();
    m = fmaxf(fmaxf(red[0], red[1]), fmaxf(red[2], red[3]));
    __syncthreads();   // before reusing red[]

    float p[8];
    float s = 0.f;
    #pragma unroll
    for (int i = 0; i < 8; ++i) {
        p[i] = __expf(e[i] - m);   // FLOAT_MIN rows underflow to exactly 0
        s += p[i];
    }
    #pragma unroll
    for (int off = 32; off > 0; off >>= 1) s += __shfl_down(s, off, 64);
    if ((t & 63) == 0) red[t >> 6] = s;
    __syncthreads();
    s = red[0] + red[1] + red[2] + red[3];

    const float inv = 1.0f / s;
    #pragma unroll
    for (int i = 0; i < 8; ++i) {
        const int l = t + i * 256;
        out[(size_t)b * L_SEQ + l] = p[i] * inv;
    }
}

// ---------------------------------------------------------------------------
extern "C" void kernel_launch(void* const* d_in, const int* in_sizes, int n_in,
                              void* d_out, int out_size, void* d_ws, size_t ws_size,
                              hipStream_t stream) {
    const float* hidden  = (const float*)d_in[0];  // (1,B,H)
    const float* enc     = (const float*)d_in[1];  // (L,B,H)
    const float* W       = (const float*)d_in[2];  // (H,H)
    const float* bias    = (const float*)d_in[3];  // (H,)
    const int*   lengths = (const int*)d_in[4];    // (B,)
    float* out = (float*)d_out;                    // (B,1,L) fp32

    // workspace layout: v[B*H] | c[B] | energies[B*L]   (~393 KB)
    float* v        = (float*)d_ws;
    float* c        = v + BATCH * HID;
    float* energies = c + BATCH;

    proj_kernel   <<<256,        256, 0, stream>>>(hidden, W, bias, v, c);
    energy_kernel <<<BATCH * 32, 256, 0, stream>>>(enc, v, c, energies);
    softmax_kernel<<<BATCH,      256, 0, stream>>>(energies, lengths, out);
}

// Round 4
// 387.219 us; speedup vs baseline: 1.0078x; 1.0078x over previous
//
#include <hip/hip_runtime.h>

#define L_SEQ 2048
#define BATCH 32
#define HID   1024
#define FLOAT_MIN -1e20f

// ---------------------------------------------------------------------------
// Kernel 1: v[b,h] = sum_g hidden[b,g] * W[g,h];  c[b] = sum_g hidden[b,g]*bias[g]
// Grid: 256 blocks -> b = bid/8, n-tile(128 cols) = bid%8. 256 threads.
// W column-tile is re-read per b but stays L2/L3 resident (W = 4 MB total).
// ---------------------------------------------------------------------------
__global__ __launch_bounds__(256) void proj_kernel(
    const float* __restrict__ hidden,   // [B,H]
    const float* __restrict__ W,        // [H,H]  (g-major, h contiguous)
    const float* __restrict__ bias,     // [H]
    float* __restrict__ v,              // [B,H]
    float* __restrict__ c)              // [B]
{
    __shared__ float  sh_hidden[HID];
    __shared__ float4 sh_part[8][32];
    __shared__ float  sh_red[4];

    const int b  = blockIdx.x >> 3;
    const int nt = blockIdx.x & 7;
    const int t  = threadIdx.x;

    // stage hidden[b,:] (4 KB) into LDS
    ((float4*)sh_hidden)[t] = ((const float4*)(hidden + (size_t)b * HID))[t];
    __syncthreads();

    const int j4   = t & 31;    // float4 column within the 128-col tile
    const int half = t >> 5;    // 0..7 : k-partition of 128 rows each
    const int n0   = nt * 128;

    float4 acc = make_float4(0.f, 0.f, 0.f, 0.f);
    const int kbase = half * 128;
    #pragma unroll 4
    for (int k = kbase; k < kbase + 128; ++k) {
        const float  hg = sh_hidden[k];                          // LDS broadcast
        const float4 w  = ((const float4*)(W + (size_t)k * HID + n0))[j4];
        acc.x += hg * w.x; acc.y += hg * w.y;
        acc.z += hg * w.z; acc.w += hg * w.w;
    }
    sh_part[half][j4] = acc;
    __syncthreads();

    if (t < 32) {
        float4 s = sh_part[0][t];
        #pragma unroll
        for (int h = 1; h < 8; ++h) {
            const float4 p = sh_part[h][t];
            s.x += p.x; s.y += p.y; s.z += p.z; s.w += p.w;
        }
        ((float4*)(v + (size_t)b * HID + n0))[t] = s;
    }

    if (nt == 0) {  // block-uniform branch: compute c[b] once per b
        float p = 0.f;
        #pragma unroll
        for (int g = t; g < HID; g += 256) p += sh_hidden[g] * bias[g];
        #pragma unroll
        for (int off = 32; off > 0; off >>= 1) p += __shfl_down(p, off, 64);
        if ((t & 63) == 0) sh_red[t >> 6] = p;
        __syncthreads();
        if (t == 0) c[b] = sh_red[0] + sh_red[1] + sh_red[2] + sh_red[3];
    }
}

// ---------------------------------------------------------------------------
// Kernel 2: energies[b,l] = v[b] . enc[l,b,:] + c[b]
// R2 flat-stream layout (best measured), REVERSED block order: the harness
// restores enc (268 MB) immediately before the timed replay, leaving the
// TAIL of enc resident in the 256 MiB L3. Reading tail-first harvests those
// hits before eviction; the cold head comes from HBM at the end.
// One wave per enc row r = l*B + b, TWO rows per wave; block of 4 waves
// covers 8 consecutive rows = 32 KB contiguous (descending across blocks).
// ---------------------------------------------------------------------------
__global__ __launch_bounds__(256) void energy_kernel(
    const float* __restrict__ enc,      // [L,B,H] = [L*B rows][H]
    const float* __restrict__ v,        // [B,H]
    const float* __restrict__ c,        // [B]
    float* __restrict__ energies)       // [B,L]
{
    const int t    = threadIdx.x;
    const int wave = t >> 6;
    const int lane = t & 63;

    const int bid = gridDim.x - 1 - blockIdx.x;   // tail-first sweep
    const int r0 = bid * 8 + wave;                // first row for this wave
    const int r1 = r0 + 4;                        // second row (in-block span)
    const int b0 = r0 & (BATCH - 1), l0 = r0 >> 5;
    const int b1 = r1 & (BATCH - 1), l1 = r1 >> 5;

    const float4* e0 = (const float4*)(enc + (size_t)r0 * HID);
    const float4* e1 = (const float4*)(enc + (size_t)r1 * HID);
    const float4* v0 = (const float4*)(v + (size_t)b0 * HID);
    const float4* v1 = (const float4*)(v + (size_t)b1 * HID);

    float a0 = 0.f, a1 = 0.f;
    #pragma unroll
    for (int j = 0; j < 4; ++j) {
        const int idx = j * 64 + lane;
        const float4 ea = e0[idx];
        const float4 eb = e1[idx];
        const float4 va = v0[idx];
        const float4 vb = v1[idx];
        a0 += ea.x * va.x + ea.y * va.y + ea.z * va.z + ea.w * va.w;
        a1 += eb.x * vb.x + eb.y * vb.y + eb.z * vb.z + eb.w * vb.w;
    }
    #pragma unroll
    for (int off = 32; off > 0; off >>= 1) {
        a0 += __shfl_down(a0, off, 64);
        a1 += __shfl_down(a1, off, 64);
    }
    if (lane == 0) {
        energies[(size_t)b0 * L_SEQ + l0] = a0 + c[b0];
        energies[(size_t)b1 * L_SEQ + l1] = a1 + c[b1];
    }
}

// ---------------------------------------------------------------------------
// Kernel 3: masked softmax per batch row, renormalized over valid positions.
// Invalid l get energy FLOAT_MIN -> exp underflows to exact 0, so plain
// softmax over the masked energies equals the reference's masked/sums.
// Grid: B blocks, 256 threads, 8 elements/thread.
// ---------------------------------------------------------------------------
__global__ __launch_bounds__(256) void softmax_kernel(
    const float* __restrict__ energies, // [B,L]
    const int*   __restrict__ lengths,  // [B]
    float* __restrict__ out)            // [B,1,L]
{
    __shared__ float red[4];

    const int b   = blockIdx.x;
    const int t   = threadIdx.x;
    const int len = lengths[b];

    float e[8];
    float m = -INFINITY;
    #pragma unroll
    for (int i = 0; i < 8; ++i) {
        const int l = t + i * 256;
        e[i] = (l < len) ? energies[(size_t)b * L_SEQ + l] : FLOAT_MIN;
        m = fmaxf(m, e[i]);
    }
    #pragma unroll
    for (int off = 32; off > 0; off >>= 1) m = fmaxf(m, __shfl_down(m, off, 64));
    if ((t & 63) == 0) red[t >> 6] = m;
    __syncthreads();
    m = fmaxf(fmaxf(red[0], red[1]), fmaxf(red[2], red[3]));
    __syncthreads();   // before reusing red[]

    float p[8];
    float s = 0.f;
    #pragma unroll
    for (int i = 0; i < 8; ++i) {
        p[i] = __expf(e[i] - m);   // FLOAT_MIN rows underflow to exactly 0
        s += p[i];
    }
    #pragma unroll
    for (int off = 32; off > 0; off >>= 1) s += __shfl_down(s, off, 64);
    if ((t & 63) == 0) red[t >> 6] = s;
    __syncthreads();
    s = red[0] + red[1] + red[2] + red[3];

    const float inv = 1.0f / s;
    #pragma unroll
    for (int i = 0; i < 8; ++i) {
        const int l = t + i * 256;
        out[(size_t)b * L_SEQ + l] = p[i] * inv;
    }
}

// ---------------------------------------------------------------------------
extern "C" void kernel_launch(void* const* d_in, const int* in_sizes, int n_in,
                              void* d_out, int out_size, void* d_ws, size_t ws_size,
                              hipStream_t stream) {
    const float* hidden  = (const float*)d_in[0];  // (1,B,H)
    const float* enc     = (const float*)d_in[1];  // (L,B,H)
    const float* W       = (const float*)d_in[2];  // (H,H)
    const float* bias    = (const float*)d_in[3];  // (H,)
    const int*   lengths = (const int*)d_in[4];    // (B,)
    float* out = (float*)d_out;                    // (B,1,L) fp32

    // workspace layout: v[B*H] | c[B] | energies[B*L]   (~393 KB)
    float* v        = (float*)d_ws;
    float* c        = v + BATCH * HID;
    float* energies = c + BATCH;

    proj_kernel   <<<256,                 256, 0, stream>>>(hidden, W, bias, v, c);
    energy_kernel <<<(L_SEQ * BATCH) / 8, 256, 0, stream>>>(enc, v, c, energies);
    softmax_kernel<<<BATCH,               256, 0, stream>>>(energies, lengths, out);
}

// Round 5
// 371.460 us; speedup vs baseline: 1.0506x; 1.0424x over previous
//
#include <hip/hip_runtime.h>

#define L_SEQ 2048
#define BATCH 32
#define HID   1024
#define FLOAT_MIN -1e20f

// ---------------------------------------------------------------------------
// Kernel 1: v[b,h] = sum_g hidden[b,g] * W[g,h];  c[b] = sum_g hidden[b,g]*bias[g]
// Grid: 256 blocks -> b = bid/8, n-tile(128 cols) = bid%8. 256 threads.
// W column-tile is re-read per b but stays L2/L3 resident (W = 4 MB total).
// ---------------------------------------------------------------------------
__global__ __launch_bounds__(256) void proj_kernel(
    const float* __restrict__ hidden,   // [B,H]
    const float* __restrict__ W,        // [H,H]  (g-major, h contiguous)
    const float* __restrict__ bias,     // [H]
    float* __restrict__ v,              // [B,H]
    float* __restrict__ c)              // [B]
{
    __shared__ float  sh_hidden[HID];
    __shared__ float4 sh_part[8][32];
    __shared__ float  sh_red[4];

    const int b  = blockIdx.x >> 3;
    const int nt = blockIdx.x & 7;
    const int t  = threadIdx.x;

    // stage hidden[b,:] (4 KB) into LDS
    ((float4*)sh_hidden)[t] = ((const float4*)(hidden + (size_t)b * HID))[t];
    __syncthreads();

    const int j4   = t & 31;    // float4 column within the 128-col tile
    const int half = t >> 5;    // 0..7 : k-partition of 128 rows each
    const int n0   = nt * 128;

    float4 acc = make_float4(0.f, 0.f, 0.f, 0.f);
    const int kbase = half * 128;
    #pragma unroll 4
    for (int k = kbase; k < kbase + 128; ++k) {
        const float  hg = sh_hidden[k];                          // LDS broadcast
        const float4 w  = ((const float4*)(W + (size_t)k * HID + n0))[j4];
        acc.x += hg * w.x; acc.y += hg * w.y;
        acc.z += hg * w.z; acc.w += hg * w.w;
    }
    sh_part[half][j4] = acc;
    __syncthreads();

    if (t < 32) {
        float4 s = sh_part[0][t];
        #pragma unroll
        for (int h = 1; h < 8; ++h) {
            const float4 p = sh_part[h][t];
            s.x += p.x; s.y += p.y; s.z += p.z; s.w += p.w;
        }
        ((float4*)(v + (size_t)b * HID + n0))[t] = s;
    }

    if (nt == 0) {  // block-uniform branch: compute c[b] once per b
        float p = 0.f;
        #pragma unroll
        for (int g = t; g < HID; g += 256) p += sh_hidden[g] * bias[g];
        #pragma unroll
        for (int off = 32; off > 0; off >>= 1) p += __shfl_down(p, off, 64);
        if ((t & 63) == 0) sh_red[t >> 6] = p;
        __syncthreads();
        if (t == 0) c[b] = sh_red[0] + sh_red[1] + sh_red[2] + sh_red[3];
    }
}

// ---------------------------------------------------------------------------
// Kernel 2: energies[b,l] = v[b] . enc[l,b,:] + c[b]   -- ONLY for l < len[b].
// Rows with l >= lengths[b] contribute exactly 0 to the output (softmax
// substitutes FLOAT_MIN without reading energies), so we skip their 4 KB
// enc read entirely: ~25% of the 268 MB stream eliminated (lengths in
// [L/2, L]). Skip decision is wave-uniform; remaining stream stays
// row-contiguous and fully coalesced.
// One wave per enc row r = l*B + b, TWO rows per wave; block of 4 waves
// covers 8 consecutive rows = 32 KB contiguous.
// ---------------------------------------------------------------------------
__global__ __launch_bounds__(256) void energy_kernel(
    const float* __restrict__ enc,      // [L,B,H] = [L*B rows][H]
    const float* __restrict__ v,        // [B,H]
    const float* __restrict__ c,        // [B]
    const int*   __restrict__ lengths,  // [B]
    float* __restrict__ energies)       // [B,L]
{
    const int t    = threadIdx.x;
    const int wave = t >> 6;
    const int lane = t & 63;

    const int r0 = blockIdx.x * 8 + wave;       // first row for this wave
    const int r1 = r0 + 4;                      // second row (in-block span)
    const int b0 = r0 & (BATCH - 1), l0 = r0 >> 5;
    const int b1 = r1 & (BATCH - 1), l1 = r1 >> 5;

    const bool do0 = l0 < lengths[b0];
    const bool do1 = l1 < lengths[b1];
    if (!do0 && !do1) return;

    float a0 = 0.f, a1 = 0.f;
    if (do0 && do1) {                   // hot path: both rows valid, full ILP
        const float4* e0 = (const float4*)(enc + (size_t)r0 * HID);
        const float4* e1 = (const float4*)(enc + (size_t)r1 * HID);
        const float4* v0 = (const float4*)(v + (size_t)b0 * HID);
        const float4* v1 = (const float4*)(v + (size_t)b1 * HID);
        #pragma unroll
        for (int j = 0; j < 4; ++j) {
            const int idx = j * 64 + lane;
            const float4 ea = e0[idx];
            const float4 eb = e1[idx];
            const float4 va = v0[idx];
            const float4 vb = v1[idx];
            a0 += ea.x * va.x + ea.y * va.y + ea.z * va.z + ea.w * va.w;
            a1 += eb.x * vb.x + eb.y * vb.y + eb.z * vb.z + eb.w * vb.w;
        }
    } else {                            // boundary: exactly one row valid
        const int rr = do0 ? r0 : r1;
        const int bb = do0 ? b0 : b1;
        const float4* e0 = (const float4*)(enc + (size_t)rr * HID);
        const float4* v0 = (const float4*)(v + (size_t)bb * HID);
        #pragma unroll
        for (int j = 0; j < 4; ++j) {
            const int idx = j * 64 + lane;
            const float4 ea = e0[idx];
            const float4 va = v0[idx];
            a0 += ea.x * va.x + ea.y * va.y + ea.z * va.z + ea.w * va.w;
        }
        a1 = a0;                        // route to whichever slot is valid
    }
    #pragma unroll
    for (int off = 32; off > 0; off >>= 1) {
        a0 += __shfl_down(a0, off, 64);
        a1 += __shfl_down(a1, off, 64);
    }
    if (lane == 0) {
        if (do0) energies[(size_t)b0 * L_SEQ + l0] = a0 + c[b0];
        if (do1) energies[(size_t)b1 * L_SEQ + l1] = a1 + c[b1];
    }
}

// ---------------------------------------------------------------------------
// Kernel 3: masked softmax per batch row, renormalized over valid positions.
// Invalid l get energy FLOAT_MIN -> exp underflows to exact 0, so plain
// softmax over the masked energies equals the reference's masked/sums.
// energies[l >= len] is never read (it was never written).
// Grid: B blocks, 256 threads, 8 elements/thread.
// ---------------------------------------------------------------------------
__global__ __launch_bounds__(256) void softmax_kernel(
    const float* __restrict__ energies, // [B,L]
    const int*   __restrict__ lengths,  // [B]
    float* __restrict__ out)            // [B,1,L]
{
    __shared__ float red[4];

    const int b   = blockIdx.x;
    const int t   = threadIdx.x;
    const int len = lengths[b];

    float e[8];
    float m = -INFINITY;
    #pragma unroll
    for (int i = 0; i < 8; ++i) {
        const int l = t + i * 256;
        e[i] = (l < len) ? energies[(size_t)b * L_SEQ + l] : FLOAT_MIN;
        m = fmaxf(m, e[i]);
    }
    #pragma unroll
    for (int off = 32; off > 0; off >>= 1) m = fmaxf(m, __shfl_down(m, off, 64));
    if ((t & 63) == 0) red[t >> 6] = m;
    __syncthreads();
    m = fmaxf(fmaxf(red[0], red[1]), fmaxf(red[2], red[3]));
    __syncthreads();   // before reusing red[]

    float p[8];
    float s = 0.f;
    #pragma unroll
    for (int i = 0; i < 8; ++i) {
        p[i] = __expf(e[i] - m);   // FLOAT_MIN rows underflow to exactly 0
        s += p[i];
    }
    #pragma unroll
    for (int off = 32; off > 0; off >>= 1) s += __shfl_down(s, off, 64);
    if ((t & 63) == 0) red[t >> 6] = s;
    __syncthreads();
    s = red[0] + red[1] + red[2] + red[3];

    const float inv = 1.0f / s;
    #pragma unroll
    for (int i = 0; i < 8; ++i) {
        const int l = t + i * 256;
        out[(size_t)b * L_SEQ + l] = p[i] * inv;
    }
}

// ---------------------------------------------------------------------------
extern "C" void kernel_launch(void* const* d_in, const int* in_sizes, int n_in,
                              void* d_out, int out_size, void* d_ws, size_t ws_size,
                              hipStream_t stream) {
    const float* hidden  = (const float*)d_in[0];  // (1,B,H)
    const float* enc     = (const float*)d_in[1];  // (L,B,H)
    const float* W       = (const float*)d_in[2];  // (H,H)
    const float* bias    = (const float*)d_in[3];  // (H,)
    const int*   lengths = (const int*)d_in[4];    // (B,)
    float* out = (float*)d_out;                    // (B,1,L) fp32

    // workspace layout: v[B*H] | c[B] | energies[B*L]   (~393 KB)
    float* v        = (float*)d_ws;
    float* c        = v + BATCH * HID;
    float* energies = c + BATCH;

    proj_kernel   <<<256,                 256, 0, stream>>>(hidden, W, bias, v, c);
    energy_kernel <<<(L_SEQ * BATCH) / 8, 256, 0, stream>>>(enc, v, c, lengths, energies);
    softmax_kernel<<<BATCH,               256, 0, stream>>>(energies, lengths, out);
}

// Round 6
// 369.802 us; speedup vs baseline: 1.0553x; 1.0045x over previous
//
#include <hip/hip_runtime.h>

#define L_SEQ 2048
#define BATCH 32
#define HID   1024
#define FLOAT_MIN -1e20f

// ---------------------------------------------------------------------------
// Kernel 1: v[b,h] = sum_g hidden[b,g] * W[g,h];  c[b] = sum_g hidden[b,g]*bias[g]
// Grid: 256 blocks -> b = bid/8, n-tile(128 cols) = bid%8. 256 threads.
// W column-tile is re-read per b but stays L2/L3 resident (W = 4 MB total).
// ---------------------------------------------------------------------------
__global__ __launch_bounds__(256) void proj_kernel(
    const float* __restrict__ hidden,   // [B,H]
    const float* __restrict__ W,        // [H,H]  (g-major, h contiguous)
    const float* __restrict__ bias,     // [H]
    float* __restrict__ v,              // [B,H]
    float* __restrict__ c)              // [B]
{
    __shared__ float  sh_hidden[HID];
    __shared__ float4 sh_part[8][32];
    __shared__ float  sh_red[4];

    const int b  = blockIdx.x >> 3;
    const int nt = blockIdx.x & 7;
    const int t  = threadIdx.x;

    // stage hidden[b,:] (4 KB) into LDS
    ((float4*)sh_hidden)[t] = ((const float4*)(hidden + (size_t)b * HID))[t];
    __syncthreads();

    const int j4   = t & 31;    // float4 column within the 128-col tile
    const int half = t >> 5;    // 0..7 : k-partition of 128 rows each
    const int n0   = nt * 128;

    float4 acc = make_float4(0.f, 0.f, 0.f, 0.f);
    const int kbase = half * 128;
    #pragma unroll 4
    for (int k = kbase; k < kbase + 128; ++k) {
        const float  hg = sh_hidden[k];                          // LDS broadcast
        const float4 w  = ((const float4*)(W + (size_t)k * HID + n0))[j4];
        acc.x += hg * w.x; acc.y += hg * w.y;
        acc.z += hg * w.z; acc.w += hg * w.w;
    }
    sh_part[half][j4] = acc;
    __syncthreads();

    if (t < 32) {
        float4 s = sh_part[0][t];
        #pragma unroll
        for (int h = 1; h < 8; ++h) {
            const float4 p = sh_part[h][t];
            s.x += p.x; s.y += p.y; s.z += p.z; s.w += p.w;
        }
        ((float4*)(v + (size_t)b * HID + n0))[t] = s;
    }

    if (nt == 0) {  // block-uniform branch: compute c[b] once per b
        float p = 0.f;
        #pragma unroll
        for (int g = t; g < HID; g += 256) p += sh_hidden[g] * bias[g];
        #pragma unroll
        for (int off = 32; off > 0; off >>= 1) p += __shfl_down(p, off, 64);
        if ((t & 63) == 0) sh_red[t >> 6] = p;
        __syncthreads();
        if (t == 0) c[b] = sh_red[0] + sh_red[1] + sh_red[2] + sh_red[3];
    }
}

// ---------------------------------------------------------------------------
// Kernel 2: energies[b,l] = v[b] . enc[l,b,:] + c[b]   -- ONLY for l < len[b].
// FOUR rows per wave: block of 4 waves covers 16 consecutive rows (64 KB
// contiguous). Wave w handles rows base+w+4i, i=0..3: 16 enc dwordx4 loads
// issued up-front (deep vmcnt queue), and the 6-step shuffle-reduce chain
// carries 4 independent accumulators (chain latency amortized 4x) -- this
// targets the ~4.2 TB/s effective stream rate seen in R5 (vs 6.3 peak).
// Valid-row skip (~25% of rows, lengths in [L/2,L]) is wave-uniform.
// v re-read per row from L2 (measured free in R2/R3).
// ---------------------------------------------------------------------------
__global__ __launch_bounds__(256) void energy_kernel(
    const float* __restrict__ enc,      // [L,B,H] = [L*B rows][H]
    const float* __restrict__ v,        // [B,H]
    const float* __restrict__ c,        // [B]
    const int*   __restrict__ lengths,  // [B]
    float* __restrict__ energies)       // [B,L]
{
    const int t    = threadIdx.x;
    const int wave = t >> 6;
    const int lane = t & 63;

    const int rbase = blockIdx.x * 16 + wave;   // rows rbase + 4*i

    int  r[4], b[4], l[4];
    bool ok[4];
    #pragma unroll
    for (int i = 0; i < 4; ++i) {
        r[i]  = rbase + 4 * i;
        b[i]  = r[i] & (BATCH - 1);
        l[i]  = r[i] >> 5;
        ok[i] = l[i] < lengths[b[i]];   // wave-uniform
    }
    if (!ok[0] && !ok[1] && !ok[2] && !ok[3]) return;

    // Phase 1: issue all enc loads (HBM, long latency) for valid rows
    float4 e[4][4];
    #pragma unroll
    for (int i = 0; i < 4; ++i) {
        if (ok[i]) {
            const float4* ep = (const float4*)(enc + (size_t)r[i] * HID);
            #pragma unroll
            for (int j = 0; j < 4; ++j) e[i][j] = ep[j * 64 + lane];
        }
    }

    // Phase 2: v loads (L2-resident) + dot
    float acc[4] = {0.f, 0.f, 0.f, 0.f};
    #pragma unroll
    for (int i = 0; i < 4; ++i) {
        if (ok[i]) {
            const float4* vp = (const float4*)(v + (size_t)b[i] * HID);
            #pragma unroll
            for (int j = 0; j < 4; ++j) {
                const float4 vv = vp[j * 64 + lane];
                const float4 ee = e[i][j];
                acc[i] += ee.x * vv.x + ee.y * vv.y + ee.z * vv.z + ee.w * vv.w;
            }
        }
    }

    // Phase 3: 4 independent shuffle reductions (chain latency amortized)
    #pragma unroll
    for (int off = 32; off > 0; off >>= 1) {
        #pragma unroll
        for (int i = 0; i < 4; ++i) acc[i] += __shfl_down(acc[i], off, 64);
    }

    if (lane == 0) {
        #pragma unroll
        for (int i = 0; i < 4; ++i)
            if (ok[i]) energies[(size_t)b[i] * L_SEQ + l[i]] = acc[i] + c[b[i]];
    }
}

// ---------------------------------------------------------------------------
// Kernel 3: masked softmax per batch row, renormalized over valid positions.
// Invalid l get energy FLOAT_MIN -> exp underflows to exact 0, so plain
// softmax over the masked energies equals the reference's masked/sums.
// energies[l >= len] is never read (it was never written).
// Grid: B blocks, 256 threads, 8 elements/thread.
// ---------------------------------------------------------------------------
__global__ __launch_bounds__(256) void softmax_kernel(
    const float* __restrict__ energies, // [B,L]
    const int*   __restrict__ lengths,  // [B]
    float* __restrict__ out)            // [B,1,L]
{
    __shared__ float red[4];

    const int b   = blockIdx.x;
    const int t   = threadIdx.x;
    const int len = lengths[b];

    float e[8];
    float m = -INFINITY;
    #pragma unroll
    for (int i = 0; i < 8; ++i) {
        const int l = t + i * 256;
        e[i] = (l < len) ? energies[(size_t)b * L_SEQ + l] : FLOAT_MIN;
        m = fmaxf(m, e[i]);
    }
    #pragma unroll
    for (int off = 32; off > 0; off >>= 1) m = fmaxf(m, __shfl_down(m, off, 64));
    if ((t & 63) == 0) red[t >> 6] = m;
    __syncthreads();
    m = fmaxf(fmaxf(red[0], red[1]), fmaxf(red[2], red[3]));
    __syncthreads();   // before reusing red[]

    float p[8];
    float s = 0.f;
    #pragma unroll
    for (int i = 0; i < 8; ++i) {
        p[i] = __expf(e[i] - m);   // FLOAT_MIN rows underflow to exactly 0
        s += p[i];
    }
    #pragma unroll
    for (int off = 32; off > 0; off >>= 1) s += __shfl_down(s, off, 64);
    if ((t & 63) == 0) red[t >> 6] = s;
    __syncthreads();
    s = red[0] + red[1] + red[2] + red[3];

    const float inv = 1.0f / s;
    #pragma unroll
    for (int i = 0; i < 8; ++i) {
        const int l = t + i * 256;
        out[(size_t)b * L_SEQ + l] = p[i] * inv;
    }
}

// ---------------------------------------------------------------------------
extern "C" void kernel_launch(void* const* d_in, const int* in_sizes, int n_in,
                              void* d_out, int out_size, void* d_ws, size_t ws_size,
                              hipStream_t stream) {
    const float* hidden  = (const float*)d_in[0];  // (1,B,H)
    const float* enc     = (const float*)d_in[1];  // (L,B,H)
    const float* W       = (const float*)d_in[2];  // (H,H)
    const float* bias    = (const float*)d_in[3];  // (H,)
    const int*   lengths = (const int*)d_in[4];    // (B,)
    float* out = (float*)d_out;                    // (B,1,L) fp32

    // workspace layout: v[B*H] | c[B] | energies[B*L]   (~393 KB)
    float* v        = (float*)d_ws;
    float* c        = v + BATCH * HID;
    float* energies = c + BATCH;

    proj_kernel   <<<256,                  256, 0, stream>>>(hidden, W, bias, v, c);
    energy_kernel <<<(L_SEQ * BATCH) / 16, 256, 0, stream>>>(enc, v, c, lengths, energies);
    softmax_kernel<<<BATCH,                256, 0, stream>>>(energies, lengths, out);
}